// Round 1
// baseline (690.450 us; speedup 1.0000x reference)
//
#include <hip/hip_runtime.h>

#define NUM_Q 4096
#define MAX_STEP 200
#define NBATCH 64
#define NT 199            // MAX_STEP - 1
#define EPS 1e-8f

// One block per (b, t) row. 256 threads; each thread processes 4 float4 groups
// (4 * 4 * 256 = 4096 = NUM_Q elements per row). All loads coalesced 16B/lane.
__global__ __launch_bounds__(256) void loss_kernel(const float* __restrict__ pred,
                                                   const float* __restrict__ batch,
                                                   float* __restrict__ out) {
    const int row = blockIdx.x;          // 0 .. NBATCH*NT - 1
    const int b = row / NT;
    const int t = row % NT;

    const float4* __restrict__ predRow =
        (const float4*)(pred + (size_t)row * NUM_Q);
    const float* batchRow =
        batch + ((size_t)b * MAX_STEP + (size_t)(t + 1)) * (size_t)(2 * NUM_Q);
    const float4* __restrict__ mqRow  = (const float4*)(batchRow);
    const float4* __restrict__ mnqRow = (const float4*)(batchRow + NUM_Q);

    float acc = 0.0f;
    #pragma unroll
    for (int i = 0; i < 4; ++i) {
        const int idx = threadIdx.x + i * 256;   // float4 index within row
        float4 p  = predRow[idx];
        float4 mq = mqRow[idx];
        float4 mn = mnqRow[idx];
        acc += mq.x * __logf(p.x + EPS) + mn.x * __logf(1.0f - p.x + EPS);
        acc += mq.y * __logf(p.y + EPS) + mn.y * __logf(1.0f - p.y + EPS);
        acc += mq.z * __logf(p.z + EPS) + mn.z * __logf(1.0f - p.z + EPS);
        acc += mq.w * __logf(p.w + EPS) + mn.w * __logf(1.0f - p.w + EPS);
    }

    // Wave (64-lane) shuffle reduction
    #pragma unroll
    for (int off = 32; off > 0; off >>= 1)
        acc += __shfl_down(acc, off, 64);

    __shared__ float smem[4];
    const int lane = threadIdx.x & 63;
    const int wave = threadIdx.x >> 6;
    if (lane == 0) smem[wave] = acc;
    __syncthreads();
    if (threadIdx.x == 0) {
        float s = smem[0] + smem[1] + smem[2] + smem[3];
        atomicAdd(out, -s);   // loss = -sum(...)
    }
}

extern "C" void kernel_launch(void* const* d_in, const int* in_sizes, int n_in,
                              void* d_out, int out_size, void* d_ws, size_t ws_size,
                              hipStream_t stream) {
    const float* pred  = (const float*)d_in[0];
    const float* batch = (const float*)d_in[1];
    float* out = (float*)d_out;

    // d_out is poisoned (0xAA) before every timed replay; zero it on-stream.
    hipMemsetAsync(out, 0, sizeof(float), stream);

    loss_kernel<<<NBATCH * NT, 256, 0, stream>>>(pred, batch, out);
}

// Round 2
// 640.927 us; speedup vs baseline: 1.0773x; 1.0773x over previous
//
#include <hip/hip_runtime.h>

#define NUM_Q 4096
#define MAX_STEP 200
#define NBATCH 64
#define NT 199                          // MAX_STEP - 1
#define EPS 1e-8f
#define NQ4 (NUM_Q / 4)                 // 1024 float4 per row
#define TOTAL_V4 (NBATCH * NT * NQ4)    // 13,041,664 float4 groups
#define NBLK 1024                       // main-kernel grid; also #partials

// Stage 1: grid-stride over all float4 groups. pred is fully contiguous;
// batch row for (b,t) starts at ((b*200 + t + 1) * 8192). Row decomposition
// uses power-of-two shifts (NQ4 = 1024); b = row/199 is one magic-mul.
// Per-block partial sum -> blockSums[blockIdx.x] (no atomics).
__global__ __launch_bounds__(256) void loss_main(const float* __restrict__ pred,
                                                 const float* __restrict__ batch,
                                                 float* __restrict__ blockSums) {
    const float4* __restrict__ pred4 = (const float4*)pred;
    const int stride = NBLK * 256;

    float acc = 0.0f;
    for (int g = blockIdx.x * 256 + threadIdx.x; g < TOTAL_V4; g += stride) {
        const int row = g >> 10;        // / NQ4
        const int r   = g & (NQ4 - 1);
        const int b   = row / NT;       // magic multiply
        const int t   = row - b * NT;
        const float4* __restrict__ bq =
            (const float4*)(batch + ((size_t)(b * MAX_STEP + t + 1) << 13));

        float4 p  = pred4[g];
        float4 mq = bq[r];
        float4 mn = bq[r + NQ4];
        acc += mq.x * __logf(p.x + EPS) + mn.x * __logf(1.0f - p.x + EPS);
        acc += mq.y * __logf(p.y + EPS) + mn.y * __logf(1.0f - p.y + EPS);
        acc += mq.z * __logf(p.z + EPS) + mn.z * __logf(1.0f - p.z + EPS);
        acc += mq.w * __logf(p.w + EPS) + mn.w * __logf(1.0f - p.w + EPS);
    }

    // 64-lane wave reduction
    #pragma unroll
    for (int off = 32; off > 0; off >>= 1)
        acc += __shfl_down(acc, off, 64);

    __shared__ float smem[4];
    const int lane = threadIdx.x & 63;
    const int wave = threadIdx.x >> 6;
    if (lane == 0) smem[wave] = acc;
    __syncthreads();
    if (threadIdx.x == 0)
        blockSums[blockIdx.x] = smem[0] + smem[1] + smem[2] + smem[3];
}

// Stage 2: one block reduces the 1024 partials; writes -sum (the loss).
__global__ __launch_bounds__(256) void loss_final(const float* __restrict__ blockSums,
                                                  float* __restrict__ out) {
    float acc = 0.0f;
    #pragma unroll
    for (int k = 0; k < NBLK / 256; ++k)
        acc += blockSums[threadIdx.x + k * 256];

    #pragma unroll
    for (int off = 32; off > 0; off >>= 1)
        acc += __shfl_down(acc, off, 64);

    __shared__ float smem[4];
    const int lane = threadIdx.x & 63;
    const int wave = threadIdx.x >> 6;
    if (lane == 0) smem[wave] = acc;
    __syncthreads();
    if (threadIdx.x == 0)
        out[0] = -(smem[0] + smem[1] + smem[2] + smem[3]);
}

extern "C" void kernel_launch(void* const* d_in, const int* in_sizes, int n_in,
                              void* d_out, int out_size, void* d_ws, size_t ws_size,
                              hipStream_t stream) {
    const float* pred  = (const float*)d_in[0];
    const float* batch = (const float*)d_in[1];
    float* blockSums   = (float*)d_ws;     // 4 KB of the workspace
    float* out         = (float*)d_out;

    loss_main<<<NBLK, 256, 0, stream>>>(pred, batch, blockSums);
    loss_final<<<1, 256, 0, stream>>>(blockSums, out);
}